// Round 18
// baseline (60.193 us; speedup 1.0000x reference)
//
#include <hip/hip_runtime.h>
#include <hip/hip_bf16.h>
#include <stdint.h>

#define LRELU_ALPHA 0.2f

constexpr int BB = 8, NN = 2048, FIN = 128, FOUT = 64;
constexpr int GEMM_ROWS = 32;
constexpr int NBLK_G = BB * NN / GEMM_ROWS;   // 512 blocks / partial maxes

typedef __attribute__((ext_vector_type(8))) short short8;
typedef __attribute__((ext_vector_type(4))) float f32x4;
typedef __attribute__((ext_vector_type(2))) float f32x2;

__device__ __forceinline__ ushort bf16rn(float f) {
    __hip_bfloat16 h = __float2bfloat16(f);
    return *reinterpret_cast<ushort*>(&h);
}

// non-temporal float4 load: stream-once data must not evict the L2 reuse set
__device__ __forceinline__ f32x4 ntload4(const float* p) {
    return __builtin_nontemporal_load(reinterpret_cast<const f32x4*>(p));
}

// ---------------- Kernel 1: Wh = h @ W (fp32) -> packed bf16 WhP + s1/s2/pmax
// (verified; unchanged since r5)
#define HS 132
__global__ __launch_bounds__(256) void k_gemm_hw(const float* __restrict__ h,
                                                 const float* __restrict__ W,
                                                 const float* __restrict__ a,
                                                 ushort* __restrict__ WhP,
                                                 float* __restrict__ s1,
                                                 float* __restrict__ s2,
                                                 float* __restrict__ pmax) {
    __shared__ float hs[GEMM_ROWS * HS];
    __shared__ __align__(16) ushort fragbuf[2048];
    __shared__ float smax[16];
    const int tid = threadIdx.x;
    const int base = blockIdx.x * GEMM_ROWS;

    #pragma unroll
    for (int rep = 0; rep < 4; ++rep) {
        int flat4 = rep * 256 + tid;
        int row = flat4 >> 5, k4 = flat4 & 31;
        float4 v = *reinterpret_cast<const float4*>(h + (size_t)(base + row) * FIN + k4 * 4);
        *reinterpret_cast<float4*>(&hs[row * HS + k4 * 4]) = v;
    }
    __syncthreads();

    const int tr = tid >> 4;
    const int tc = tid & 15;
    float acc[2][4] = {};
    #pragma unroll 4
    for (int k = 0; k < FIN; ++k) {
        float4 wv = *reinterpret_cast<const float4*>(W + (size_t)k * FOUT + tc * 4);
        #pragma unroll
        for (int r = 0; r < 2; ++r) {
            float hv = hs[(tr * 2 + r) * HS + k];
            acc[r][0] = fmaf(hv, wv.x, acc[r][0]);
            acc[r][1] = fmaf(hv, wv.y, acc[r][1]);
            acc[r][2] = fmaf(hv, wv.z, acc[r][2]);
            acc[r][3] = fmaf(hv, wv.w, acc[r][3]);
        }
    }

    #pragma unroll
    for (int r = 0; r < 2; ++r) {
        const int jloc = tr * 2 + r;
        const int e = jloc & 7, kgrp = jloc >> 3;
        #pragma unroll
        for (int c = 0; c < 4; ++c) {
            const int col = tc * 4 + c;
            fragbuf[((col >> 4) * 64 + kgrp * 16 + (col & 15)) * 8 + e] = bf16rn(acc[r][c]);
        }
    }

    float a1c[4], a2c[4];
    #pragma unroll
    for (int c = 0; c < 4; ++c) {
        a1c[c] = a[tc * 4 + c];
        a2c[c] = a[FOUT + tc * 4 + c];
    }
    float maxp2 = -3.4e38f;
    #pragma unroll
    for (int r = 0; r < 2; ++r) {
        float p1 = acc[r][0] * a1c[0] + acc[r][1] * a1c[1] + acc[r][2] * a1c[2] + acc[r][3] * a1c[3];
        float p2 = acc[r][0] * a2c[0] + acc[r][1] * a2c[1] + acc[r][2] * a2c[2] + acc[r][3] * a2c[3];
        #pragma unroll
        for (int off = 1; off < 16; off <<= 1) {
            p1 += __shfl_xor(p1, off);
            p2 += __shfl_xor(p2, off);
        }
        if (tc == 0) {
            s1[base + tr * 2 + r] = p1;
            s2[base + tr * 2 + r] = p2;
            maxp2 = fmaxf(maxp2, p2);
        }
    }
    if (tc == 0) smax[tr] = maxp2;
    __syncthreads();

    const size_t region = ((size_t)((base >> 11) * 64 + ((base & 2047) >> 5))) * 2048;
    *reinterpret_cast<uint4*>(WhP + region + tid * 8) =
        *reinterpret_cast<const uint4*>(fragbuf + tid * 8);

    if (tid == 0) {
        float mm = smax[0];
        #pragma unroll
        for (int i = 1; i < 16; ++i) mm = fmaxf(mm, smax[i]);
        pmax[blockIdx.x] = mm;
    }
}

// packed pair: w = adj * max(e1p*E2p, e1n*E2n), round-half-up bf16, pack 2->1
__device__ __forceinline__ uint32_t wvpk(float ax, float ay, float px, float py,
                                         float nx, float ny, float e1p, float e1n) {
    f32x2 t1 = f32x2{e1p, e1p} * f32x2{px, py};
    f32x2 t2 = f32x2{e1n, e1n} * f32x2{nx, ny};
    f32x2 mx = {fmaxf(t1.x, t2.x), fmaxf(t1.y, t2.y)};
    f32x2 w2 = f32x2{ax, ay} * mx;
    uint32_t u0 = __float_as_uint(w2.x) + 0x8000u;
    uint32_t u1 = __float_as_uint(w2.y) + 0x8000u;
    return __builtin_amdgcn_perm(u1, u0, 0x07060302);
}

// ---------------- Kernel 2: separable-exp masked softmax + MFMA PV ----------
// r17 body (best measured). SINGLE CHANGE: adj loads are NON-TEMPORAL (nt)
// so the 134 MB stream-once adj traffic does not evict the L2 reuse set
// (WhP, re-read ~128x/batch); out stores likewise non-temporal.
__global__ __launch_bounds__(256, 4) void k_attn(const float* __restrict__ adj,
                                                 const ushort* __restrict__ WhP,
                                                 const float* __restrict__ s1,
                                                 const float* __restrict__ s2,
                                                 const float* __restrict__ pmax,
                                                 float* __restrict__ out) {
    __shared__ float e2p[NN];           // 8 KB
    __shared__ float e2n[NN];           // 8 KB
    __shared__ float lacc[4][16][68];
    __shared__ float lS[4][16];

    const int tid = threadIdx.x;
    const int l = tid & 63, w = tid >> 6;      // w in [0,4)
    const int li = l & 15, lk = l >> 4;
    const int blk = blockIdx.x;
    const int b = blk >> 7;
    const int rowbase = blk * 16;
    const int row_i = rowbase + li;

    // global max m2 of s2 from 512 partials (L2-hot)
    float m = -3.4e38f;
    #pragma unroll
    for (int t = 0; t < 8; ++t) m = fmaxf(m, pmax[l + 64 * t]);
    #pragma unroll
    for (int off = 32; off > 0; off >>= 1) m = fmaxf(m, __shfl_xor(m, off));

    // fill SoA E2 tables (8 j per thread)
    const float* __restrict__ s2B = s2 + (size_t)b * NN;
    #pragma unroll
    for (int k = 0; k < 8; ++k) {
        const int j = k * 256 + tid;
        const float d = s2B[j] - m;
        e2p[j] = __expf(d);
        e2n[j] = __expf(LRELU_ALPHA * d);
    }

    const float s1i = s1[row_i];
    const float cp = s1i + m;
    const float e1p = __expf(0.8f * fminf(cp, 0.f));
    const float e1n = __expf(-0.8f * fmaxf(cp, 0.f));

    __syncthreads();

    const float* __restrict__ adjp = adj + (size_t)row_i * NN + w * 512 + lk * 8;
    const ushort* __restrict__ whp = WhP + (size_t)b * 131072 + (size_t)(w * 16) * 2048 + l * 8;
    const float* __restrict__ e2pw = e2p + w * 512 + lk * 8;
    const float* __restrict__ e2nw = e2n + w * 512 + lk * 8;

    f32x4 acc0 = {0.f, 0.f, 0.f, 0.f};
    f32x4 acc1 = {0.f, 0.f, 0.f, 0.f};
    f32x4 acc2 = {0.f, 0.f, 0.f, 0.f};
    f32x4 acc3 = {0.f, 0.f, 0.f, 0.f};
    f32x4 accS = {0.f, 0.f, 0.f, 0.f};
    short8 ones;
    #pragma unroll
    for (int e = 0; e < 8; ++e) ones[e] = (short)0x3F80;   // bf16 1.0

    // ping-pong set A (even tiles) and set B (odd tiles); adj loads are NT
    f32x4 aA0 = ntload4(adjp);
    f32x4 aA1 = ntload4(adjp + 4);
    short8 bA0 = *reinterpret_cast<const short8*>(whp);
    short8 bA1 = *reinterpret_cast<const short8*>(whp + 512);
    short8 bA2 = *reinterpret_cast<const short8*>(whp + 1024);
    short8 bA3 = *reinterpret_cast<const short8*>(whp + 1536);
    f32x4 aB0 = ntload4(adjp + 32);
    f32x4 aB1 = ntload4(adjp + 36);
    short8 bB0 = *reinterpret_cast<const short8*>(whp + 2048);
    short8 bB1 = *reinterpret_cast<const short8*>(whp + 2048 + 512);
    short8 bB2 = *reinterpret_cast<const short8*>(whp + 2048 + 1024);
    short8 bB3 = *reinterpret_cast<const short8*>(whp + 2048 + 1536);

#define DOETILE(A0, A1, B0, B1, B2, B3, TIDX) do {                            \
        const float4* pp_ = reinterpret_cast<const float4*>(e2pw + (TIDX) * 32); \
        const float4* nn_ = reinterpret_cast<const float4*>(e2nw + (TIDX) * 32); \
        const float4 p0_ = pp_[0], p1_ = pp_[1];                              \
        const float4 n0_ = nn_[0], n1_ = nn_[1];                              \
        uint32_t k0_ = wvpk((A0)[0], (A0)[1], p0_.x, p0_.y, n0_.x, n0_.y, e1p, e1n); \
        uint32_t k1_ = wvpk((A0)[2], (A0)[3], p0_.z, p0_.w, n0_.z, n0_.w, e1p, e1n); \
        uint32_t k2_ = wvpk((A1)[0], (A1)[1], p1_.x, p1_.y, n1_.x, n1_.y, e1p, e1n); \
        uint32_t k3_ = wvpk((A1)[2], (A1)[3], p1_.z, p1_.w, n1_.z, n1_.w, e1p, e1n); \
        int4 afw_ = make_int4((int)k0_, (int)k1_, (int)k2_, (int)k3_);        \
        short8 af_ = *reinterpret_cast<short8*>(&afw_);                       \
        acc0 = __builtin_amdgcn_mfma_f32_16x16x32_bf16(af_, (B0), acc0, 0, 0, 0); \
        acc1 = __builtin_amdgcn_mfma_f32_16x16x32_bf16(af_, (B1), acc1, 0, 0, 0); \
        acc2 = __builtin_amdgcn_mfma_f32_16x16x32_bf16(af_, (B2), acc2, 0, 0, 0); \
        acc3 = __builtin_amdgcn_mfma_f32_16x16x32_bf16(af_, (B3), acc3, 0, 0, 0); \
        accS = __builtin_amdgcn_mfma_f32_16x16x32_bf16(af_, ones, accS, 0, 0, 0); \
    } while (0)

    for (int t = 0; t < 16; t += 2) {
        // prefetch tile t+2 (even) into temps; clamp -> harmless reload of t
        const int t2 = (t + 2 < 16) ? t + 2 : t;
        f32x4 nA0 = ntload4(adjp + t2 * 32);
        f32x4 nA1 = ntload4(adjp + t2 * 32 + 4);
        const ushort* npA = whp + t2 * 2048;
        short8 nbA0 = *reinterpret_cast<const short8*>(npA);
        short8 nbA1 = *reinterpret_cast<const short8*>(npA + 512);
        short8 nbA2 = *reinterpret_cast<const short8*>(npA + 1024);
        short8 nbA3 = *reinterpret_cast<const short8*>(npA + 1536);

        DOETILE(aA0, aA1, bA0, bA1, bA2, bA3, t);
        aA0 = nA0; aA1 = nA1;
        bA0 = nbA0; bA1 = nbA1; bA2 = nbA2; bA3 = nbA3;

        // prefetch tile t+3 (odd) into temps; clamp -> harmless reload of t+1
        const int t3 = (t + 3 < 16) ? t + 3 : t + 1;
        f32x4 nB0 = ntload4(adjp + t3 * 32);
        f32x4 nB1 = ntload4(adjp + t3 * 32 + 4);
        const ushort* npB = whp + t3 * 2048;
        short8 nbB0 = *reinterpret_cast<const short8*>(npB);
        short8 nbB1 = *reinterpret_cast<const short8*>(npB + 512);
        short8 nbB2 = *reinterpret_cast<const short8*>(npB + 1024);
        short8 nbB3 = *reinterpret_cast<const short8*>(npB + 1536);

        DOETILE(aB0, aB1, bB0, bB1, bB2, bB3, t + 1);
        aB0 = nB0; aB1 = nB1;
        bB0 = nbB0; bB1 = nbB1; bB2 = nbB2; bB3 = nbB3;
    }
#undef DOETILE

    // accS is in D layout: accS[r] = S(row lk*4+r) on every lane
    if (li == 0) {
        #pragma unroll
        for (int r = 0; r < 4; ++r) lS[w][lk * 4 + r] = accS[r];
    }
    #pragma unroll
    for (int r = 0; r < 4; ++r) {
        lacc[w][lk * 4 + r][0 * 16 + li] = acc0[r];
        lacc[w][lk * 4 + r][1 * 16 + li] = acc1[r];
        lacc[w][lk * 4 + r][2 * 16 + li] = acc2[r];
        lacc[w][lk * 4 + r][3 * 16 + li] = acc3[r];
    }
    __syncthreads();

    #pragma unroll
    for (int q = 0; q < 4; ++q) {
        const int idx = q * 256 + tid;
        const int row = idx >> 6, col = idx & 63;
        float v = lacc[0][row][col] + lacc[1][row][col] + lacc[2][row][col] + lacc[3][row][col];
        float S = lS[0][row] + lS[1][row] + lS[2][row] + lS[3][row];
        float o = v / S;
        o = o > 0.f ? o : expm1f(o);
        __builtin_nontemporal_store(o, &out[(size_t)(rowbase + row) * FOUT + col]);
    }
}

// ---------------------------------------------------------------------------
extern "C" void kernel_launch(void* const* d_in, const int* in_sizes, int n_in,
                              void* d_out, int out_size, void* d_ws, size_t ws_size,
                              hipStream_t stream) {
    (void)in_sizes; (void)n_in; (void)out_size; (void)ws_size;
    const float* h   = (const float*)d_in[0];
    const float* adj = (const float*)d_in[1];
    const float* W   = (const float*)d_in[2];
    const float* a   = (const float*)d_in[3];
    float* out = (float*)d_out;

    ushort* WhP = (ushort*)d_ws;                          // 2 MB
    float* s1w  = (float*)(WhP + (size_t)BB * NN * FOUT);
    float* s2w  = s1w + (size_t)BB * NN;
    float* pmaxw = s2w + (size_t)BB * NN;                 // NBLK_G floats

    k_gemm_hw<<<NBLK_G, 256, 0, stream>>>(h, W, a, WhP, s1w, s2w, pmaxw);
    k_attn<<<BB * NN / 16, 256, 0, stream>>>(adj, WhP, s1w, s2w, pmaxw, out);
}

// Round 19
// 44.954 us; speedup vs baseline: 1.3390x; 1.3390x over previous
//
#include <hip/hip_runtime.h>
#include <hip/hip_bf16.h>
#include <stdint.h>

#define LRELU_ALPHA 0.2f

constexpr int BB = 8, NN = 2048, FIN = 128, FOUT = 64;
constexpr int GEMM_ROWS = 32;
constexpr int NBLK_G = BB * NN / GEMM_ROWS;   // 512 blocks / partial maxes

typedef __attribute__((ext_vector_type(8))) short short8;
typedef __attribute__((ext_vector_type(4))) float f32x4;
typedef __attribute__((ext_vector_type(2))) float f32x2;

__device__ __forceinline__ ushort bf16rn(float f) {
    __hip_bfloat16 h = __float2bfloat16(f);
    return *reinterpret_cast<ushort*>(&h);
}

// ---------------- Kernel 1: Wh = h @ W (fp32) -> packed bf16 WhP + s1/s2/pmax
// (verified; unchanged since r5)
#define HS 132
__global__ __launch_bounds__(256) void k_gemm_hw(const float* __restrict__ h,
                                                 const float* __restrict__ W,
                                                 const float* __restrict__ a,
                                                 ushort* __restrict__ WhP,
                                                 float* __restrict__ s1,
                                                 float* __restrict__ s2,
                                                 float* __restrict__ pmax) {
    __shared__ float hs[GEMM_ROWS * HS];
    __shared__ __align__(16) ushort fragbuf[2048];
    __shared__ float smax[16];
    const int tid = threadIdx.x;
    const int base = blockIdx.x * GEMM_ROWS;

    #pragma unroll
    for (int rep = 0; rep < 4; ++rep) {
        int flat4 = rep * 256 + tid;
        int row = flat4 >> 5, k4 = flat4 & 31;
        float4 v = *reinterpret_cast<const float4*>(h + (size_t)(base + row) * FIN + k4 * 4);
        *reinterpret_cast<float4*>(&hs[row * HS + k4 * 4]) = v;
    }
    __syncthreads();

    const int tr = tid >> 4;
    const int tc = tid & 15;
    float acc[2][4] = {};
    #pragma unroll 4
    for (int k = 0; k < FIN; ++k) {
        float4 wv = *reinterpret_cast<const float4*>(W + (size_t)k * FOUT + tc * 4);
        #pragma unroll
        for (int r = 0; r < 2; ++r) {
            float hv = hs[(tr * 2 + r) * HS + k];
            acc[r][0] = fmaf(hv, wv.x, acc[r][0]);
            acc[r][1] = fmaf(hv, wv.y, acc[r][1]);
            acc[r][2] = fmaf(hv, wv.z, acc[r][2]);
            acc[r][3] = fmaf(hv, wv.w, acc[r][3]);
        }
    }

    #pragma unroll
    for (int r = 0; r < 2; ++r) {
        const int jloc = tr * 2 + r;
        const int e = jloc & 7, kgrp = jloc >> 3;
        #pragma unroll
        for (int c = 0; c < 4; ++c) {
            const int col = tc * 4 + c;
            fragbuf[((col >> 4) * 64 + kgrp * 16 + (col & 15)) * 8 + e] = bf16rn(acc[r][c]);
        }
    }

    float a1c[4], a2c[4];
    #pragma unroll
    for (int c = 0; c < 4; ++c) {
        a1c[c] = a[tc * 4 + c];
        a2c[c] = a[FOUT + tc * 4 + c];
    }
    float maxp2 = -3.4e38f;
    #pragma unroll
    for (int r = 0; r < 2; ++r) {
        float p1 = acc[r][0] * a1c[0] + acc[r][1] * a1c[1] + acc[r][2] * a1c[2] + acc[r][3] * a1c[3];
        float p2 = acc[r][0] * a2c[0] + acc[r][1] * a2c[1] + acc[r][2] * a2c[2] + acc[r][3] * a2c[3];
        #pragma unroll
        for (int off = 1; off < 16; off <<= 1) {
            p1 += __shfl_xor(p1, off);
            p2 += __shfl_xor(p2, off);
        }
        if (tc == 0) {
            s1[base + tr * 2 + r] = p1;
            s2[base + tr * 2 + r] = p2;
            maxp2 = fmaxf(maxp2, p2);
        }
    }
    if (tc == 0) smax[tr] = maxp2;
    __syncthreads();

    const size_t region = ((size_t)((base >> 11) * 64 + ((base & 2047) >> 5))) * 2048;
    *reinterpret_cast<uint4*>(WhP + region + tid * 8) =
        *reinterpret_cast<const uint4*>(fragbuf + tid * 8);

    if (tid == 0) {
        float mm = smax[0];
        #pragma unroll
        for (int i = 1; i < 16; ++i) mm = fmaxf(mm, smax[i]);
        pmax[blockIdx.x] = mm;
    }
}

// packed pair: w = adj * max(e1p*E2p, e1n*E2n), round-half-up bf16, pack 2->1
__device__ __forceinline__ uint32_t wvpk(float ax, float ay, float px, float py,
                                         float nx, float ny, float e1p, float e1n) {
    f32x2 t1 = f32x2{e1p, e1p} * f32x2{px, py};
    f32x2 t2 = f32x2{e1n, e1n} * f32x2{nx, ny};
    f32x2 mx = {fmaxf(t1.x, t2.x), fmaxf(t1.y, t2.y)};
    f32x2 w2 = f32x2{ax, ay} * mx;
    uint32_t u0 = __float_as_uint(w2.x) + 0x8000u;
    uint32_t u1 = __float_as_uint(w2.y) + 0x8000u;
    return __builtin_amdgcn_perm(u1, u0, 0x07060302);
}

// ---------------- Kernel 2: separable-exp masked softmax + MFMA PV ----------
// LOCKED BEST (r17, 44.98us): r13 body + depth-2 A/B ping-pong prefetch.
// 16 rows/block, 4 waves x 512-j, (256,4), SoA e2 LDS tables, wvpk pack,
// ones-MFMA S. Cached (temporal) loads -- NT regressed 34% (r18): adj's L3
// residency across replays is load-bearing.
__global__ __launch_bounds__(256, 4) void k_attn(const float* __restrict__ adj,
                                                 const ushort* __restrict__ WhP,
                                                 const float* __restrict__ s1,
                                                 const float* __restrict__ s2,
                                                 const float* __restrict__ pmax,
                                                 float* __restrict__ out) {
    __shared__ float e2p[NN];           // 8 KB
    __shared__ float e2n[NN];           // 8 KB
    __shared__ float lacc[4][16][68];
    __shared__ float lS[4][16];

    const int tid = threadIdx.x;
    const int l = tid & 63, w = tid >> 6;      // w in [0,4)
    const int li = l & 15, lk = l >> 4;
    const int blk = blockIdx.x;
    const int b = blk >> 7;
    const int rowbase = blk * 16;
    const int row_i = rowbase + li;

    // global max m2 of s2 from 512 partials (L2-hot)
    float m = -3.4e38f;
    #pragma unroll
    for (int t = 0; t < 8; ++t) m = fmaxf(m, pmax[l + 64 * t]);
    #pragma unroll
    for (int off = 32; off > 0; off >>= 1) m = fmaxf(m, __shfl_xor(m, off));

    // fill SoA E2 tables (8 j per thread)
    const float* __restrict__ s2B = s2 + (size_t)b * NN;
    #pragma unroll
    for (int k = 0; k < 8; ++k) {
        const int j = k * 256 + tid;
        const float d = s2B[j] - m;
        e2p[j] = __expf(d);
        e2n[j] = __expf(LRELU_ALPHA * d);
    }

    const float s1i = s1[row_i];
    const float cp = s1i + m;
    const float e1p = __expf(0.8f * fminf(cp, 0.f));
    const float e1n = __expf(-0.8f * fmaxf(cp, 0.f));

    __syncthreads();

    const float* __restrict__ adjp = adj + (size_t)row_i * NN + w * 512 + lk * 8;
    const ushort* __restrict__ whp = WhP + (size_t)b * 131072 + (size_t)(w * 16) * 2048 + l * 8;
    const float* __restrict__ e2pw = e2p + w * 512 + lk * 8;
    const float* __restrict__ e2nw = e2n + w * 512 + lk * 8;

    f32x4 acc0 = {0.f, 0.f, 0.f, 0.f};
    f32x4 acc1 = {0.f, 0.f, 0.f, 0.f};
    f32x4 acc2 = {0.f, 0.f, 0.f, 0.f};
    f32x4 acc3 = {0.f, 0.f, 0.f, 0.f};
    f32x4 accS = {0.f, 0.f, 0.f, 0.f};
    short8 ones;
    #pragma unroll
    for (int e = 0; e < 8; ++e) ones[e] = (short)0x3F80;   // bf16 1.0

    // ping-pong set A (even tiles) and set B (odd tiles)
    float4 aA0 = *reinterpret_cast<const float4*>(adjp);
    float4 aA1 = *reinterpret_cast<const float4*>(adjp + 4);
    short8 bA0 = *reinterpret_cast<const short8*>(whp);
    short8 bA1 = *reinterpret_cast<const short8*>(whp + 512);
    short8 bA2 = *reinterpret_cast<const short8*>(whp + 1024);
    short8 bA3 = *reinterpret_cast<const short8*>(whp + 1536);
    float4 aB0 = *reinterpret_cast<const float4*>(adjp + 32);
    float4 aB1 = *reinterpret_cast<const float4*>(adjp + 36);
    short8 bB0 = *reinterpret_cast<const short8*>(whp + 2048);
    short8 bB1 = *reinterpret_cast<const short8*>(whp + 2048 + 512);
    short8 bB2 = *reinterpret_cast<const short8*>(whp + 2048 + 1024);
    short8 bB3 = *reinterpret_cast<const short8*>(whp + 2048 + 1536);

#define DOETILE(A0, A1, B0, B1, B2, B3, TIDX) do {                            \
        const float4* pp_ = reinterpret_cast<const float4*>(e2pw + (TIDX) * 32); \
        const float4* nn_ = reinterpret_cast<const float4*>(e2nw + (TIDX) * 32); \
        const float4 p0_ = pp_[0], p1_ = pp_[1];                              \
        const float4 n0_ = nn_[0], n1_ = nn_[1];                              \
        uint32_t k0_ = wvpk((A0).x, (A0).y, p0_.x, p0_.y, n0_.x, n0_.y, e1p, e1n); \
        uint32_t k1_ = wvpk((A0).z, (A0).w, p0_.z, p0_.w, n0_.z, n0_.w, e1p, e1n); \
        uint32_t k2_ = wvpk((A1).x, (A1).y, p1_.x, p1_.y, n1_.x, n1_.y, e1p, e1n); \
        uint32_t k3_ = wvpk((A1).z, (A1).w, p1_.z, p1_.w, n1_.z, n1_.w, e1p, e1n); \
        int4 afw_ = make_int4((int)k0_, (int)k1_, (int)k2_, (int)k3_);        \
        short8 af_ = *reinterpret_cast<short8*>(&afw_);                       \
        acc0 = __builtin_amdgcn_mfma_f32_16x16x32_bf16(af_, (B0), acc0, 0, 0, 0); \
        acc1 = __builtin_amdgcn_mfma_f32_16x16x32_bf16(af_, (B1), acc1, 0, 0, 0); \
        acc2 = __builtin_amdgcn_mfma_f32_16x16x32_bf16(af_, (B2), acc2, 0, 0, 0); \
        acc3 = __builtin_amdgcn_mfma_f32_16x16x32_bf16(af_, (B3), acc3, 0, 0, 0); \
        accS = __builtin_amdgcn_mfma_f32_16x16x32_bf16(af_, ones, accS, 0, 0, 0); \
    } while (0)

    for (int t = 0; t < 16; t += 2) {
        // prefetch tile t+2 (even) into temps; clamp -> harmless reload of t
        const int t2 = (t + 2 < 16) ? t + 2 : t;
        float4 nA0 = *reinterpret_cast<const float4*>(adjp + t2 * 32);
        float4 nA1 = *reinterpret_cast<const float4*>(adjp + t2 * 32 + 4);
        const ushort* npA = whp + t2 * 2048;
        short8 nbA0 = *reinterpret_cast<const short8*>(npA);
        short8 nbA1 = *reinterpret_cast<const short8*>(npA + 512);
        short8 nbA2 = *reinterpret_cast<const short8*>(npA + 1024);
        short8 nbA3 = *reinterpret_cast<const short8*>(npA + 1536);

        DOETILE(aA0, aA1, bA0, bA1, bA2, bA3, t);
        aA0 = nA0; aA1 = nA1;
        bA0 = nbA0; bA1 = nbA1; bA2 = nbA2; bA3 = nbA3;

        // prefetch tile t+3 (odd) into temps; clamp -> harmless reload of t+1
        const int t3 = (t + 3 < 16) ? t + 3 : t + 1;
        float4 nB0 = *reinterpret_cast<const float4*>(adjp + t3 * 32);
        float4 nB1 = *reinterpret_cast<const float4*>(adjp + t3 * 32 + 4);
        const ushort* npB = whp + t3 * 2048;
        short8 nbB0 = *reinterpret_cast<const short8*>(npB);
        short8 nbB1 = *reinterpret_cast<const short8*>(npB + 512);
        short8 nbB2 = *reinterpret_cast<const short8*>(npB + 1024);
        short8 nbB3 = *reinterpret_cast<const short8*>(npB + 1536);

        DOETILE(aB0, aB1, bB0, bB1, bB2, bB3, t + 1);
        aB0 = nB0; aB1 = nB1;
        bB0 = nbB0; bB1 = nbB1; bB2 = nbB2; bB3 = nbB3;
    }
#undef DOETILE

    // accS is in D layout: accS[r] = S(row lk*4+r) on every lane
    if (li == 0) {
        #pragma unroll
        for (int r = 0; r < 4; ++r) lS[w][lk * 4 + r] = accS[r];
    }
    #pragma unroll
    for (int r = 0; r < 4; ++r) {
        lacc[w][lk * 4 + r][0 * 16 + li] = acc0[r];
        lacc[w][lk * 4 + r][1 * 16 + li] = acc1[r];
        lacc[w][lk * 4 + r][2 * 16 + li] = acc2[r];
        lacc[w][lk * 4 + r][3 * 16 + li] = acc3[r];
    }
    __syncthreads();

    #pragma unroll
    for (int q = 0; q < 4; ++q) {
        const int idx = q * 256 + tid;
        const int row = idx >> 6, col = idx & 63;
        float v = lacc[0][row][col] + lacc[1][row][col] + lacc[2][row][col] + lacc[3][row][col];
        float S = lS[0][row] + lS[1][row] + lS[2][row] + lS[3][row];
        float o = v / S;
        o = o > 0.f ? o : expm1f(o);
        out[(size_t)(rowbase + row) * FOUT + col] = o;
    }
}

// ---------------------------------------------------------------------------
extern "C" void kernel_launch(void* const* d_in, const int* in_sizes, int n_in,
                              void* d_out, int out_size, void* d_ws, size_t ws_size,
                              hipStream_t stream) {
    (void)in_sizes; (void)n_in; (void)out_size; (void)ws_size;
    const float* h   = (const float*)d_in[0];
    const float* adj = (const float*)d_in[1];
    const float* W   = (const float*)d_in[2];
    const float* a   = (const float*)d_in[3];
    float* out = (float*)d_out;

    ushort* WhP = (ushort*)d_ws;                          // 2 MB
    float* s1w  = (float*)(WhP + (size_t)BB * NN * FOUT);
    float* s2w  = s1w + (size_t)BB * NN;
    float* pmaxw = s2w + (size_t)BB * NN;                 // NBLK_G floats

    k_gemm_hw<<<NBLK_G, 256, 0, stream>>>(h, W, a, WhP, s1w, s2w, pmaxw);
    k_attn<<<BB * NN / 16, 256, 0, stream>>>(adj, WhP, s1w, s2w, pmaxw, out);
}